// Round 20
// baseline (268.779 us; speedup 1.0000x reference)
//
#include <hip/hip_runtime.h>

typedef unsigned short u16;
typedef __attribute__((ext_vector_type(8))) short bf16x8;
typedef __attribute__((ext_vector_type(4))) float f32x4;

__device__ __forceinline__ float bf2f(u16 u) {
  union { unsigned int i; float f; } v;
  v.i = ((unsigned int)u) << 16;
  return v.f;
}
__device__ __forceinline__ u16 f2bf(float f) {
  union { float f; unsigned int i; } v;
  v.f = f;
  unsigned int r = v.i + 0x7FFFu + ((v.i >> 16) & 1u);
  return (u16)(r >> 16);
}
// pack 2 fp32 -> 2 bf16 (flash Q-staging only; NOT in GEMM hot loops - m240)
__device__ __forceinline__ unsigned int cvtpk(float lo, float hi) {
  unsigned int r;
  asm("v_cvt_pk_bf16_f32 %0, %1, %2" : "=v"(r) : "v"(lo), "v"(hi));
  return r;
}

// 4 contiguous elements -> float4
__device__ __forceinline__ float4 ld4f(const float* p) {
  return *reinterpret_cast<const float4*>(p);
}
__device__ __forceinline__ float4 ld4f(const u16* p) {
  uint2 v = *reinterpret_cast<const uint2*>(p);
  float4 r;
  r.x = bf2f((u16)(v.x & 0xffff)); r.y = bf2f((u16)(v.x >> 16));
  r.z = bf2f((u16)(v.y & 0xffff)); r.w = bf2f((u16)(v.y >> 16));
  return r;
}

// ---------------------------------------------------------------------------
// GroupNorm: in (N,C,L) fp32-or-bf16 -> out bf16, groups=32, stats fp32.
// Optional fused: out = (gn(x) + Add) * post_scale   (Add is fp32)
// 1024 threads/block (16 waves), float4-vectorized both passes.
// ---------------------------------------------------------------------------
template <typename TIN>
__global__ __launch_bounds__(1024) void gn_kernel(
    const TIN* __restrict__ In, u16* __restrict__ OutBuf,
    const float* __restrict__ G, const float* __restrict__ Bt,
    const float* __restrict__ Add, float post_scale,
    int C, int L, int cpg)
{
  const int blk = blockIdx.x;
  const int n = blk >> 5, grp = blk & 31;
  const size_t base = ((size_t)n * C + (size_t)grp * cpg) * L;
  const int cnt = cpg * L;
  const int cnt4 = cnt >> 2;
  const int tid = threadIdx.x;

  float s = 0.f, s2 = 0.f;
  for (int i = tid; i < cnt4; i += 1024) {
    float4 v = ld4f(In + base + (size_t)i * 4);
    s += v.x + v.y + v.z + v.w;
    s2 += v.x * v.x + v.y * v.y + v.z * v.z + v.w * v.w;
  }
#pragma unroll
  for (int d = 1; d < 64; d <<= 1) {
    s += __shfl_xor(s, d);
    s2 += __shfl_xor(s2, d);
  }
  __shared__ float ps[16], ps2[16], stat[2];
  const int wid = tid >> 6;
  if ((tid & 63) == 0) { ps[wid] = s; ps2[wid] = s2; }
  __syncthreads();
  if (tid == 0) {
    float a = 0.f, b2 = 0.f;
#pragma unroll
    for (int w = 0; w < 16; ++w) { a += ps[w]; b2 += ps2[w]; }
    const float mean = a / cnt;
    const float var = b2 / cnt - mean * mean;
    stat[0] = mean;
    stat[1] = rsqrtf(var + 1e-5f);
  }
  __syncthreads();
  const float mean = stat[0], rstd = stat[1];

  for (int i = tid; i < cnt4; i += 1024) {
    const int i4 = i * 4;
    const int ch = grp * cpg + i4 / L;     // 4 elems share a channel (L%4==0)
    float4 v = ld4f(In + base + i4);
    const float g = G[ch] * rstd, bt = Bt[ch] - mean * rstd * G[ch];
    float4 r;
    r.x = v.x * g + bt; r.y = v.y * g + bt;
    r.z = v.z * g + bt; r.w = v.w * g + bt;
    if (Add) {
      float4 a = *reinterpret_cast<const float4*>(Add + base + i4);
      r.x = (r.x + a.x) * post_scale; r.y = (r.y + a.y) * post_scale;
      r.z = (r.z + a.z) * post_scale; r.w = (r.w + a.w) * post_scale;
    }
    uint2 o;
    o.x = (unsigned int)f2bf(r.x) | ((unsigned int)f2bf(r.y) << 16);
    o.y = (unsigned int)f2bf(r.z) | ((unsigned int)f2bf(r.w) << 16);
    *reinterpret_cast<uint2*>(OutBuf + base + i4) = o;
  }
}

// ---------------------------------------------------------------------------
// element loaders -> bf16 arrays (compiler-scheduled conversions, no asm)
// ---------------------------------------------------------------------------
__device__ __forceinline__ void load4(const u16* p, u16* d) {
  uint2 v = *reinterpret_cast<const uint2*>(p);
  d[0] = (u16)(v.x & 0xffff); d[1] = (u16)(v.x >> 16);
  d[2] = (u16)(v.y & 0xffff); d[3] = (u16)(v.y >> 16);
}
__device__ __forceinline__ void load4(const float* p, u16* d) {
  float4 v = *reinterpret_cast<const float4*>(p);
  d[0] = f2bf(v.x); d[1] = f2bf(v.y); d[2] = f2bf(v.z); d[3] = f2bf(v.w);
}
__device__ __forceinline__ void load8(const u16* p, u16* d) {
  union { uint4 q; u16 u[8]; } t;
  t.q = *reinterpret_cast<const uint4*>(p);
#pragma unroll
  for (int i = 0; i < 8; ++i) d[i] = t.u[i];
}

// ---------------------------------------------------------------------------
// 1x1-conv GEMM (R11-proven): Out[n,o,l] = sum_c W[o,c]*X[n,c,l] + bias[o]
// W fp32 (f2bf in staging regs). X bf16 or fp32 (TX).
// mode 0: OutBf (bf16)
// mode 1: Out32[idx] = v + Res[idx]  (fp32 residual/out; Res may alias Out32)
// Block tile 64(O) x LT(L), BK=32, 4 waves; each wave computes 16(O) x LT.
// T14 reg-prefetch: K-tile t+1's global loads issue during tile t's compute.
// L=1024 convs: grid 8x8x8 = 512 blocks = 2/CU (R17 lesson: 1/CU tiles lose).
// ---------------------------------------------------------------------------
template <typename TX, int LT>
__global__ __launch_bounds__(256) void gemm_conv(
    const TX* __restrict__ X, const float* __restrict__ W,
    const float* __restrict__ Bias,
    u16* __restrict__ OutBf, float* __restrict__ Out32,
    const float* __restrict__ Res,
    int Cin, int L, int O, int mode)
{
  constexpr int NL = LT / 16;                 // acc tiles; l per thread per ch
  __shared__ __align__(16) u16 As[64][40];    // [o][k]
  __shared__ __align__(16) u16 Bs[LT][40];    // transposed: [l][k]
  const int tid = threadIdx.x;
  const int wave = tid >> 6;
  const int lane = tid & 63;
  const int n = blockIdx.z;
  const int o0 = blockIdx.x * 64;
  const int l0 = blockIdx.y * LT;
  const TX* Xn = X + (size_t)n * Cin * L;

  // staging ownership
  const int ao = tid >> 2, akc = (tid & 3) * 8;        // A: row o, 8 k
  const int c2 = (tid & 15) * 2, lt0 = (tid >> 4) * NL; // B: 2 channels, NL l
  const float* wp = W + (size_t)(o0 + ao) * Cin + akc;
  const TX* xp0 = Xn + (size_t)c2 * L + l0 + lt0;
  const TX* xp1 = xp0 + L;

  f32x4 acc[NL];
#pragma unroll
  for (int i = 0; i < NL; ++i) acc[i] = (f32x4){0.f, 0.f, 0.f, 0.f};

  const int row = lane & 15;
  const int kh = (lane >> 4) * 8;

  // ---- prefetch K-tile 0 ----
  float4 wa = *reinterpret_cast<const float4*>(wp);
  float4 wb = *reinterpret_cast<const float4*>(wp + 4);
  u16 blo[NL], bhi[NL];
#pragma unroll
  for (int ch = 0; ch < NL; ch += 4) {
    load4(xp0 + ch, blo + ch);
    load4(xp1 + ch, bhi + ch);
  }

  const int nK = Cin >> 5;
  for (int kt = 0; kt < nK; ++kt) {
    // ---- ds_write prefetched A (b128) ----
    {
      union { uint4 q; u16 u[8]; } ap;
      ap.u[0] = f2bf(wa.x); ap.u[1] = f2bf(wa.y);
      ap.u[2] = f2bf(wa.z); ap.u[3] = f2bf(wa.w);
      ap.u[4] = f2bf(wb.x); ap.u[5] = f2bf(wb.y);
      ap.u[6] = f2bf(wb.z); ap.u[7] = f2bf(wb.w);
      *reinterpret_cast<uint4*>(&As[ao][akc]) = ap.q;
    }
    // ---- ds_write prefetched B (paired-channel u32) ----
#pragma unroll
    for (int j = 0; j < NL; ++j)
      *reinterpret_cast<unsigned int*>(&Bs[lt0 + j][c2]) =
          (unsigned int)blo[j] | ((unsigned int)bhi[j] << 16);
    __syncthreads();

    // ---- issue next K-tile's global loads (hide under compute) ----
    if (kt + 1 < nK) {
      const int k0 = (kt + 1) * 32;
      wa = *reinterpret_cast<const float4*>(wp + k0);
      wb = *reinterpret_cast<const float4*>(wp + k0 + 4);
#pragma unroll
      for (int ch = 0; ch < NL; ch += 4) {
        load4(xp0 + (size_t)k0 * L + ch, blo + ch);
        load4(xp1 + (size_t)k0 * L + ch, bhi + ch);
      }
    }

    // ---- compute ----
    bf16x8 a = *reinterpret_cast<const bf16x8*>(&As[wave * 16 + row][kh]);
#pragma unroll
    for (int lt = 0; lt < NL; ++lt) {
      bf16x8 b = *reinterpret_cast<const bf16x8*>(&Bs[lt * 16 + row][kh]);
      acc[lt] = __builtin_amdgcn_mfma_f32_16x16x32_bf16(a, b, acc[lt], 0, 0, 0);
    }
    __syncthreads();
  }

  const int col = lane & 15;
  const int r0 = (lane >> 4) * 4;
#pragma unroll
  for (int lt = 0; lt < NL; ++lt) {
    const int ll = l0 + lt * 16 + col;
#pragma unroll
    for (int j = 0; j < 4; ++j) {
      const int oo = o0 + wave * 16 + r0 + j;
      float v = acc[lt][j] + Bias[oo];
      const size_t idx = ((size_t)n * O + oo) * L + ll;
      if (mode == 1) {
        Out32[idx] = v + Res[idx];
      } else {
        OutBf[idx] = f2bf(v);
      }
    }
  }
}

// ---------------------------------------------------------------------------
// qkv GEMM: 128(O) x 128(L), BK=32, 4 waves; wave owns 32 O rows (2 groups
// of 16, flash-style) x 128 L -> 16 MFMA per wave per barrier pair (2x R11).
// Grid 12x8x8 = 768 blocks = 3/CU -- occupancy-safe for the bigger tile.
// bf16 X only, bf16 out, no residual. T14 reg-prefetch.
// ---------------------------------------------------------------------------
__global__ __launch_bounds__(256) void gemm_qkv(
    const u16* __restrict__ X, const float* __restrict__ W,
    const float* __restrict__ Bias, u16* __restrict__ OutBf,
    int Cin, int L, int O)
{
  __shared__ __align__(16) u16 As[128][40];   // [o][k]
  __shared__ __align__(16) u16 Bs[128][40];   // transposed: [l][k]
  const int tid = threadIdx.x;
  const int wave = tid >> 6;
  const int lane = tid & 63;
  const int n = blockIdx.z;
  const int o0 = blockIdx.x * 128;
  const int l0 = blockIdx.y * 128;
  const u16* Xn = X + (size_t)n * Cin * L;

  // staging ownership
  const int ao = tid >> 1, ak = (tid & 1) * 16;        // A: row o, 16 k
  const int c2 = (tid & 15) * 2, lt0 = (tid >> 4) * 8; // B: 2 ch, 8 l
  const float* wp = W + (size_t)(o0 + ao) * Cin + ak;
  const u16* xp0 = Xn + (size_t)c2 * L + l0 + lt0;
  const u16* xp1 = xp0 + L;

  f32x4 acc[2][8];
#pragma unroll
  for (int g = 0; g < 2; ++g)
#pragma unroll
    for (int i = 0; i < 8; ++i) acc[g][i] = (f32x4){0.f, 0.f, 0.f, 0.f};

  const int row = lane & 15;
  const int kh = (lane >> 4) * 8;

  // ---- prefetch K-tile 0 ----
  float4 w0 = *reinterpret_cast<const float4*>(wp);
  float4 w1 = *reinterpret_cast<const float4*>(wp + 4);
  float4 w2 = *reinterpret_cast<const float4*>(wp + 8);
  float4 w3 = *reinterpret_cast<const float4*>(wp + 12);
  u16 blo[8], bhi[8];
  load8(xp0, blo);
  load8(xp1, bhi);

  const int nK = Cin >> 5;
  for (int kt = 0; kt < nK; ++kt) {
    // ---- ds_write prefetched A (2 x b128) ----
    {
      union { uint4 q; u16 u[8]; } ap;
      ap.u[0] = f2bf(w0.x); ap.u[1] = f2bf(w0.y);
      ap.u[2] = f2bf(w0.z); ap.u[3] = f2bf(w0.w);
      ap.u[4] = f2bf(w1.x); ap.u[5] = f2bf(w1.y);
      ap.u[6] = f2bf(w1.z); ap.u[7] = f2bf(w1.w);
      *reinterpret_cast<uint4*>(&As[ao][ak]) = ap.q;
      ap.u[0] = f2bf(w2.x); ap.u[1] = f2bf(w2.y);
      ap.u[2] = f2bf(w2.z); ap.u[3] = f2bf(w2.w);
      ap.u[4] = f2bf(w3.x); ap.u[5] = f2bf(w3.y);
      ap.u[6] = f2bf(w3.z); ap.u[7] = f2bf(w3.w);
      *reinterpret_cast<uint4*>(&As[ao][ak + 8]) = ap.q;
    }
    // ---- ds_write prefetched B (8 paired-channel u32) ----
#pragma unroll
    for (int j = 0; j < 8; ++j)
      *reinterpret_cast<unsigned int*>(&Bs[lt0 + j][c2]) =
          (unsigned int)blo[j] | ((unsigned int)bhi[j] << 16);
    __syncthreads();

    // ---- issue next K-tile's global loads (hide under compute) ----
    if (kt + 1 < nK) {
      const int k0 = (kt + 1) * 32;
      w0 = *reinterpret_cast<const float4*>(wp + k0);
      w1 = *reinterpret_cast<const float4*>(wp + k0 + 4);
      w2 = *reinterpret_cast<const float4*>(wp + k0 + 8);
      w3 = *reinterpret_cast<const float4*>(wp + k0 + 12);
      load8(xp0 + (size_t)k0 * L, blo);
      load8(xp1 + (size_t)k0 * L, bhi);
    }

    // ---- compute: 2 A-groups x 8 B-tiles = 16 MFMA/wave ----
    bf16x8 a0 = *reinterpret_cast<const bf16x8*>(&As[wave * 32 + row][kh]);
    bf16x8 a1 = *reinterpret_cast<const bf16x8*>(&As[wave * 32 + 16 + row][kh]);
#pragma unroll
    for (int lt = 0; lt < 8; ++lt) {
      bf16x8 b = *reinterpret_cast<const bf16x8*>(&Bs[lt * 16 + row][kh]);
      acc[0][lt] = __builtin_amdgcn_mfma_f32_16x16x32_bf16(a0, b, acc[0][lt], 0, 0, 0);
      acc[1][lt] = __builtin_amdgcn_mfma_f32_16x16x32_bf16(a1, b, acc[1][lt], 0, 0, 0);
    }
    __syncthreads();
  }

  const int col = lane & 15;
  const int r0 = (lane >> 4) * 4;
#pragma unroll
  for (int g = 0; g < 2; ++g)
#pragma unroll
    for (int lt = 0; lt < 8; ++lt) {
      const int ll = l0 + lt * 16 + col;
#pragma unroll
      for (int j = 0; j < 4; ++j) {
        const int oo = o0 + wave * 32 + g * 16 + r0 + j;
        OutBf[((size_t)n * O + oo) * L + ll] = f2bf(acc[g][lt][j] + Bias[oo]);
      }
    }
}

// ---------------------------------------------------------------------------
// MFMA flash attention, 8 waves (512 thr): XOR-swizzled LDS (T2), reg-prefetch
// staging (T14), phase-aliased 40 KB LDS, setprio (T5), exp2-domain softmax,
// defer-max (T13) with deferred max-reduction, per-lane deferred l-reduction.
// Block = (head bh, 128-query tile); WAVE OWNS 16 q-rows -> same grid (512
// blocks) now gives 16 waves/CU (was 8): 2x TLP to hide the VALU softmax.
//   phase 0: Qs[128*128] (32 KB) - staged coalesced, hoisted to regs, dead
//   phase 1: Ks[64*128] | Ps[128*64] | Vt[64*64] alias over Qs
// No launch_bounds min-waves arg (R9/R10: it throttles VGPR -> 200MB spill).
// ---------------------------------------------------------------------------
__global__ __launch_bounds__(512) void flash_attn(
    const u16* __restrict__ qA, int qA_C, int qA_off,
    const u16* __restrict__ qB,
    const u16* __restrict__ kA, int kA_C, int kA_off,
    const u16* __restrict__ kB,
    const u16* __restrict__ V, int v_C, int v_off,
    u16* __restrict__ Out, int S_len, float qscale)
{
  __shared__ __align__(16) u16 smem[20480];   // 40 KB
  u16* const Qs = smem;                        // [128*128] phase 0
  u16* const Ks = smem;                        // [64*128]  phase 1
  u16* const Ps = smem + 8192;                 // [128*64]  phase 1
  u16* const Vt = smem + 16384;                // [64*64]   phase 1

  const int tid = threadIdx.x;
  const int wave = tid >> 6, lane = tid & 63;
  const int b = blockIdx.y >> 3, h = blockIdx.y & 7;
  const int t0 = blockIdx.x * 128;
  const int l16 = lane & 15, q4 = lane >> 4;
  const int swz = (l16 & 7) << 3;

  // per-thread channel pair for Q/K staging (c2 even; c2,c2+1 same source)
  const int c2 = lane * 2;
  const u16* q0 = (c2 < 64)
      ? qA + ((size_t)b * qA_C + qA_off + h * 64 + c2) * 1024 + t0
      : qB + ((size_t)b * 512 + h * 64 + (c2 - 64)) * 1024 + t0;
  const u16* q1 = q0 + 1024;
  const u16* k0 = (c2 < 64)
      ? kA + ((size_t)b * kA_C + kA_off + h * 64 + c2) * (size_t)S_len
      : kB + ((size_t)b * 512 + h * 64 + (c2 - 64)) * (size_t)S_len;
  const u16* k1 = k0 + S_len;
  const u16* vb = V + ((size_t)b * v_C + v_off + h * 64) * (size_t)S_len;

  const int s8 = wave * 8;                  // K staging rows: s8..s8+7 (8 waves)
  const int cv = tid >> 3, sb = (tid & 7) * 8;   // V: row cv, 8 s at sb

  // ---- prefetch K/V tile 0 into regs ----
  uint4 kra = *reinterpret_cast<const uint4*>(k0 + s8);
  uint4 krc = *reinterpret_cast<const uint4*>(k1 + s8);
  uint4 vr = *reinterpret_cast<const uint4*>(vb + (size_t)cv * S_len + sb);

  // ---- phase 0: stage Q (qscale folded), paired u32 swizzled writes ----
#pragma unroll
  for (int it = 0; it < 2; ++it) {
    const int t8 = wave * 8 + it * 64;
    union { uint4 q; u16 u[8]; } a, c;
    a.q = *reinterpret_cast<const uint4*>(q0 + t8);
    c.q = *reinterpret_cast<const uint4*>(q1 + t8);
#pragma unroll
    for (int j = 0; j < 8; ++j) {
      const unsigned int w =
          cvtpk(bf2f(a.u[j]) * qscale, bf2f(c.u[j]) * qscale);
      *reinterpret_cast<unsigned int*>(&Qs[(t8 + j) * 128 + (c2 ^ (j << 3))]) = w;
    }
  }
  __syncthreads();

  // hoist Q fragments (wave owns q-rows wave*16..+15; 4 k-chunks)
  bf16x8 qf[4];
#pragma unroll
  for (int kk = 0; kk < 4; ++kk)
    qf[kk] = *reinterpret_cast<const bf16x8*>(
        &Qs[(wave * 16 + l16) * 128 + ((kk * 32 + q4 * 8) ^ swz)]);
  __syncthreads();   // Qs dead; Ks/Ps/Vt may now overwrite

  // l_run holds PER-LANE partial sums; reduced once in the epilogue.
  float m_run[4], l_run[4];
  f32x4 o_acc[4];
#pragma unroll
  for (int j = 0; j < 4; ++j) {
    m_run[j] = -1e30f; l_run[j] = 0.f;
    o_acc[j] = (f32x4){0.f, 0.f, 0.f, 0.f};
  }

  const int NT = S_len >> 6;
  for (int t = 0; t < NT; ++t) {
    // ---- ds_write prefetched K (u32 pairs, swizzled; 8 waves cover 64 s) ----
    {
      union { uint4 q; u16 u[8]; } a, c;
      a.q = kra; c.q = krc;
#pragma unroll
      for (int j = 0; j < 8; ++j)
        *reinterpret_cast<unsigned int*>(&Ks[(s8 + j) * 128 + (c2 ^ (j << 3))]) =
            (unsigned int)a.u[j] | ((unsigned int)c.u[j] << 16);
    }
    // ---- ds_write prefetched V (b128, swizzled; 512 thr cover 64x64) ----
    *reinterpret_cast<uint4*>(&Vt[cv * 64 + (sb ^ ((cv & 7) << 3))]) = vr;
    __syncthreads();

    // ---- issue next tile's global loads (complete under this tile's compute) ----
    if (t + 1 < NT) {
      const int sc = (t + 1) * 64;
      kra = *reinterpret_cast<const uint4*>(k0 + sc + s8);
      krc = *reinterpret_cast<const uint4*>(k1 + sc + s8);
      vr = *reinterpret_cast<const uint4*>(vb + (size_t)cv * S_len + sc + sb);
    }

    // ---- QK^T: S[q][s] for this wave's 16 q-rows ----
    f32x4 sacc[4];
#pragma unroll
    for (int st = 0; st < 4; ++st) sacc[st] = (f32x4){0.f, 0.f, 0.f, 0.f};
    __builtin_amdgcn_s_setprio(1);
#pragma unroll
    for (int st = 0; st < 4; ++st) {
#pragma unroll
      for (int kk = 0; kk < 4; ++kk) {
        bf16x8 kf = *reinterpret_cast<const bf16x8*>(
            &Ks[(st * 16 + l16) * 128 + ((kk * 32 + q4 * 8) ^ swz)]);
        sacc[st] = __builtin_amdgcn_mfma_f32_16x16x32_bf16(qf[kk], kf, sacc[st], 0, 0, 0);
      }
    }
    __builtin_amdgcn_s_setprio(0);

    // ---- per-lane partial max (NO cross-lane reduce on the common path) ----
    float mt[4];
#pragma unroll
    for (int j = 0; j < 4; ++j)
      mt[j] = fmaxf(fmaxf(sacc[0][j], sacc[1][j]),
                    fmaxf(sacc[2][j], sacc[3][j]));

    // ---- defer-max (T13): row-max > m+THR iff some lane's partial > m+THR ----
    bool grow = false;
#pragma unroll
    for (int j = 0; j < 4; ++j)
      grow = grow || (mt[j] > m_run[j] + 8.f);
    if (__any(grow)) {
      // full 16-lane reduce + rescale (rare; first tile always enters)
#pragma unroll
      for (int d = 1; d < 16; d <<= 1)
#pragma unroll
        for (int j = 0; j < 4; ++j)
          mt[j] = fmaxf(mt[j], __shfl_xor(mt[j], d));
#pragma unroll
      for (int j = 0; j < 4; ++j) {
        const float mn = fmaxf(m_run[j], mt[j]);
        const float corr = exp2f(m_run[j] - mn);
        m_run[j] = mn;
        l_run[j] *= corr;
#pragma unroll
        for (int ct = 0; ct < 4; ++ct) o_acc[ct][j] *= corr;
      }
    }

    // ---- P = exp2(s - m), per-lane l partials, write P (wave-private rows) ----
#pragma unroll
    for (int st = 0; st < 4; ++st)
#pragma unroll
      for (int j = 0; j < 4; ++j) {
        const float p = exp2f(sacc[st][j] - m_run[j]);
        l_run[j] += p;
        Ps[(wave * 16 + q4 * 4 + j) * 64 +
           ((st * 16 + l16) ^ (((q4 * 4 + j) & 7) << 3))] = f2bf(p);
      }

    // ---- PV: O[q][cv] += P[q][s] * V[s][cv] ----
    bf16x8 pa[2];
#pragma unroll
    for (int ks = 0; ks < 2; ++ks)
      pa[ks] = *reinterpret_cast<const bf16x8*>(
          &Ps[(wave * 16 + l16) * 64 + ((ks * 32 + q4 * 8) ^ swz)]);
    __builtin_amdgcn_s_setprio(1);
#pragma unroll
    for (int ct = 0; ct < 4; ++ct) {
#pragma unroll
      for (int ks = 0; ks < 2; ++ks) {
        bf16x8 vf = *reinterpret_cast<const bf16x8*>(
            &Vt[(ct * 16 + l16) * 64 + ((ks * 32 + q4 * 8) ^ swz)]);
        o_acc[ct] = __builtin_amdgcn_mfma_f32_16x16x32_bf16(pa[ks], vf, o_acc[ct], 0, 0, 0);
      }
    }
    __builtin_amdgcn_s_setprio(0);
    __syncthreads();  // all LDS reads done before next tile's ds_writes
  }

  // ---- epilogue: reduce l partials across 16-lane groups, O /= l, store ----
#pragma unroll
  for (int d = 1; d < 16; d <<= 1)
#pragma unroll
    for (int j = 0; j < 4; ++j) l_run[j] += __shfl_xor(l_run[j], d);
  float inv[4];
#pragma unroll
  for (int j = 0; j < 4; ++j) inv[j] = 1.f / l_run[j];
  const size_t obase =
      ((size_t)b * 512 + h * 64) * 1024 + t0 + wave * 16 + q4 * 4;
#pragma unroll
  for (int ct = 0; ct < 4; ++ct) {
    union { unsigned long long d; u16 u[4]; } pk;
#pragma unroll
    for (int j = 0; j < 4; ++j) pk.u[j] = f2bf(o_acc[ct][j] * inv[j]);
    *reinterpret_cast<unsigned long long*>(
        Out + obase + (size_t)(ct * 16 + l16) * 1024) = pk.d;
  }
}

// ---------------------------------------------------------------------------
// Workspace plan (48 MB total; all lifetimes provably disjoint, stream-ordered)
//   A [ 0, 8M): norm1(w1,r2) -> norm2(w7,r8) -> smalls(w9..12, r13)
//   B [ 8,32M): qkv(w2,r5) -> cq = B head (w8,r13)
//   C [32,40M): ipos(w4; r5,r13)
//   D [40,48M): iposr(w3,r4) -> attn1(w5,r6) -> cattn(w13,r14)
//   xf32 lives in d_out (w6; r7; r14 as Res; w14 final) — element-wise self-alias ok
// ---------------------------------------------------------------------------
extern "C" void kernel_launch(void* const* d_in, const int* in_sizes, int n_in,
                              void* d_out, int out_size, void* d_ws, size_t ws_size,
                              hipStream_t stream) {
  const float* X_in        = (const float*)d_in[0];
  const float* xf_out      = (const float*)d_in[1];
  const float* obj_cont    = (const float*)d_in[2];
  const float* obj_desc    = (const float*)d_in[3];
  const float* ipce        = (const float*)d_in[4];
  const float* gn_qkv_g    = (const float*)d_in[5];
  const float* gn_qkv_b    = (const float*)d_in[6];
  const float* W_self_qkv  = (const float*)d_in[7];
  const float* b_self_qkv  = (const float*)d_in[8];
  const float* W_cross_q   = (const float*)d_in[9];
  const float* b_cross_q   = (const float*)d_in[10];
  const float* W_content   = (const float*)d_in[11];
  const float* b_content   = (const float*)d_in[12];
  const float* W_pos       = (const float*)d_in[13];
  const float* b_pos       = (const float*)d_in[14];
  const float* gn_desc_g   = (const float*)d_in[15];
  const float* gn_desc_b   = (const float*)d_in[16];
  const float* gn_cpos_g   = (const float*)d_in[17];
  const float* gn_cpos_b   = (const float*)d_in[18];
  const float* gn_ipos_g   = (const float*)d_in[19];
  const float* gn_ipos_b   = (const float*)d_in[20];
  const float* W_self_out  = (const float*)d_in[21];
  const float* b_self_out  = (const float*)d_in[22];
  const float* W_cross_out = (const float*)d_in[23];
  const float* b_cross_out = (const float*)d_in[24];

  char* base = (char*)d_ws;
  u16* A = (u16*)base;                       // 8 MB region
  u16* B = (u16*)(base + 8 * 1024 * 1024);   // 24 MB region
  u16* C = (u16*)(base + 32 * 1024 * 1024);  // 8 MB region
  u16* D = (u16*)(base + 40 * 1024 * 1024);  // 8 MB region

  u16* norm1 = A;
  u16* norm2 = A;
  u16* cposr   = A;
  u16* cpos    = A + 262144;
  u16* content = A + 2 * 262144;
  u16* kvbuf   = A + 3 * 262144;   // 524288 elems
  u16* qkv  = B;
  u16* cq   = B;
  u16* ipos = C;
  u16* iposr = D;
  u16* attn1 = D;
  u16* cattn = D;
  float* xf32 = (float*)d_out;
  float* outp = (float*)d_out;

  // scale^2 = 128^-0.5; fold log2(e) for exp2-domain softmax
  const float qscale = 0.08838834764831845f * 1.4426950408889634f;
  dim3 blk(256);
  dim3 blkf(512);
  dim3 blkgn(1024);

  // 1. norm1 = GN(x)
  gn_kernel<float><<<dim3(256), blkgn, 0, stream>>>(X_in, norm1, gn_qkv_g, gn_qkv_b,
                                                    nullptr, 1.f, 512, 1024, 16);
  // 2. qkv = conv(norm1, W_self_qkv)  [128x128 tile, 16 MFMA/wave/iter, 3/CU]
  gemm_qkv<<<dim3(12, 8, 8), blk, 0, stream>>>(norm1, W_self_qkv, b_self_qkv,
                                               qkv, 512, 1024, 1536);
  // 3. iposr = conv(ipce, W_pos)   [64x128 tile, 2/CU]
  gemm_conv<float, 128><<<dim3(8, 8, 8), blk, 0, stream>>>(ipce, W_pos, b_pos, iposr,
                                                           nullptr, nullptr,
                                                           512, 1024, 512, 0);
  // 4. ipos = GN(iposr)
  gn_kernel<u16><<<dim3(256), blkgn, 0, stream>>>(iposr, ipos, gn_ipos_g, gn_ipos_b,
                                                  nullptr, 1.f, 512, 1024, 16);
  // 5. self-attention -> attn1 (flash MFMA, 128-q tiles, 8 waves)
  flash_attn<<<dim3(8, 64), blkf, 0, stream>>>(qkv, 1536, 0, ipos,
                                               qkv, 1536, 512, ipos,
                                               qkv, 1536, 1024,
                                               attn1, 1024, qscale);
  // 6. xf32 = x + conv(attn1, W_self_out)   [xf32 = d_out]
  gemm_conv<u16, 128><<<dim3(8, 8, 8), blk, 0, stream>>>(attn1, W_self_out, b_self_out,
                                                         nullptr, xf32, X_in,
                                                         512, 1024, 512, 1);
  // 7. norm2 = GN(xf32)
  gn_kernel<float><<<dim3(256), blkgn, 0, stream>>>(xf32, norm2, gn_qkv_g, gn_qkv_b,
                                                    nullptr, 1.f, 512, 1024, 16);
  // 8. cq = conv(norm2, W_cross_q)
  gemm_conv<u16, 128><<<dim3(8, 8, 8), blk, 0, stream>>>(norm2, W_cross_q, b_cross_q, cq,
                                                         nullptr, nullptr,
                                                         512, 1024, 512, 0);
  // 9. cposr = conv(obj_contour, W_pos)
  gemm_conv<float, 64><<<dim3(8, 1, 8), blk, 0, stream>>>(obj_cont, W_pos, b_pos, cposr,
                                                          nullptr, nullptr,
                                                          512, 64, 512, 0);
  // 10. cpos = GN(cposr)
  gn_kernel<u16><<<dim3(256), blkgn, 0, stream>>>(cposr, cpos, gn_cpos_g, gn_cpos_b,
                                                  nullptr, 1.f, 512, 64, 16);
  // 11. content = (xf_out + GN(obj_desc)) / 2
  gn_kernel<float><<<dim3(256), blkgn, 0, stream>>>(obj_desc, content, gn_desc_g,
                                                    gn_desc_b, xf_out, 0.5f, 512, 64, 16);
  // 12. kv = conv(content, W_content)
  gemm_conv<u16, 64><<<dim3(16, 1, 8), blk, 0, stream>>>(content, W_content, b_content,
                                                         kvbuf, nullptr, nullptr,
                                                         512, 64, 1024, 0);
  // 13. cross-attention -> cattn (flash MFMA, single K-tile, 8 waves)
  flash_attn<<<dim3(8, 64), blkf, 0, stream>>>(cq, 512, 0, ipos,
                                               kvbuf, 1024, 0, cpos,
                                               kvbuf, 1024, 512,
                                               cattn, 64, qscale);
  // 14. out = xf32 + conv(cattn, W_cross_out)   [in-place on d_out]
  gemm_conv<u16, 128><<<dim3(8, 8, 8), blk, 0, stream>>>(cattn, W_cross_out, b_cross_out,
                                                         nullptr, outp, xf32,
                                                         512, 1024, 512, 1);
}

// Round 21
// 247.655 us; speedup vs baseline: 1.0853x; 1.0853x over previous
//
#include <hip/hip_runtime.h>

typedef unsigned short u16;
typedef __attribute__((ext_vector_type(8))) short bf16x8;
typedef __attribute__((ext_vector_type(4))) float f32x4;

__device__ __forceinline__ float bf2f(u16 u) {
  union { unsigned int i; float f; } v;
  v.i = ((unsigned int)u) << 16;
  return v.f;
}
__device__ __forceinline__ u16 f2bf(float f) {
  union { float f; unsigned int i; } v;
  v.f = f;
  unsigned int r = v.i + 0x7FFFu + ((v.i >> 16) & 1u);
  return (u16)(r >> 16);
}
// pack 2 fp32 -> 2 bf16 (flash Q-staging only; NOT in GEMM hot loops - m240)
__device__ __forceinline__ unsigned int cvtpk(float lo, float hi) {
  unsigned int r;
  asm("v_cvt_pk_bf16_f32 %0, %1, %2" : "=v"(r) : "v"(lo), "v"(hi));
  return r;
}

// 4 contiguous elements -> float4
__device__ __forceinline__ float4 ld4f(const float* p) {
  return *reinterpret_cast<const float4*>(p);
}
__device__ __forceinline__ float4 ld4f(const u16* p) {
  uint2 v = *reinterpret_cast<const uint2*>(p);
  float4 r;
  r.x = bf2f((u16)(v.x & 0xffff)); r.y = bf2f((u16)(v.x >> 16));
  r.z = bf2f((u16)(v.y & 0xffff)); r.w = bf2f((u16)(v.y >> 16));
  return r;
}

// ---------------------------------------------------------------------------
// GroupNorm: in (N,C,L) fp32-or-bf16 -> out bf16, groups=32, stats fp32.
// Optional fused: out = (gn(x) + Add) * post_scale   (Add is fp32)
// 1024 threads/block (16 waves), float4-vectorized both passes.
// ---------------------------------------------------------------------------
template <typename TIN>
__global__ __launch_bounds__(1024) void gn_kernel(
    const TIN* __restrict__ In, u16* __restrict__ OutBuf,
    const float* __restrict__ G, const float* __restrict__ Bt,
    const float* __restrict__ Add, float post_scale,
    int C, int L, int cpg)
{
  const int blk = blockIdx.x;
  const int n = blk >> 5, grp = blk & 31;
  const size_t base = ((size_t)n * C + (size_t)grp * cpg) * L;
  const int cnt = cpg * L;
  const int cnt4 = cnt >> 2;
  const int tid = threadIdx.x;

  float s = 0.f, s2 = 0.f;
  for (int i = tid; i < cnt4; i += 1024) {
    float4 v = ld4f(In + base + (size_t)i * 4);
    s += v.x + v.y + v.z + v.w;
    s2 += v.x * v.x + v.y * v.y + v.z * v.z + v.w * v.w;
  }
#pragma unroll
  for (int d = 1; d < 64; d <<= 1) {
    s += __shfl_xor(s, d);
    s2 += __shfl_xor(s2, d);
  }
  __shared__ float ps[16], ps2[16], stat[2];
  const int wid = tid >> 6;
  if ((tid & 63) == 0) { ps[wid] = s; ps2[wid] = s2; }
  __syncthreads();
  if (tid == 0) {
    float a = 0.f, b2 = 0.f;
#pragma unroll
    for (int w = 0; w < 16; ++w) { a += ps[w]; b2 += ps2[w]; }
    const float mean = a / cnt;
    const float var = b2 / cnt - mean * mean;
    stat[0] = mean;
    stat[1] = rsqrtf(var + 1e-5f);
  }
  __syncthreads();
  const float mean = stat[0], rstd = stat[1];

  for (int i = tid; i < cnt4; i += 1024) {
    const int i4 = i * 4;
    const int ch = grp * cpg + i4 / L;     // 4 elems share a channel (L%4==0)
    float4 v = ld4f(In + base + i4);
    const float g = G[ch] * rstd, bt = Bt[ch] - mean * rstd * G[ch];
    float4 r;
    r.x = v.x * g + bt; r.y = v.y * g + bt;
    r.z = v.z * g + bt; r.w = v.w * g + bt;
    if (Add) {
      float4 a = *reinterpret_cast<const float4*>(Add + base + i4);
      r.x = (r.x + a.x) * post_scale; r.y = (r.y + a.y) * post_scale;
      r.z = (r.z + a.z) * post_scale; r.w = (r.w + a.w) * post_scale;
    }
    uint2 o;
    o.x = (unsigned int)f2bf(r.x) | ((unsigned int)f2bf(r.y) << 16);
    o.y = (unsigned int)f2bf(r.z) | ((unsigned int)f2bf(r.w) << 16);
    *reinterpret_cast<uint2*>(OutBuf + base + i4) = o;
  }
}

// ---------------------------------------------------------------------------
// element loaders -> bf16 arrays (compiler-scheduled conversions, no asm)
// ---------------------------------------------------------------------------
__device__ __forceinline__ void load4(const u16* p, u16* d) {
  uint2 v = *reinterpret_cast<const uint2*>(p);
  d[0] = (u16)(v.x & 0xffff); d[1] = (u16)(v.x >> 16);
  d[2] = (u16)(v.y & 0xffff); d[3] = (u16)(v.y >> 16);
}
__device__ __forceinline__ void load4(const float* p, u16* d) {
  float4 v = *reinterpret_cast<const float4*>(p);
  d[0] = f2bf(v.x); d[1] = f2bf(v.y); d[2] = f2bf(v.z); d[3] = f2bf(v.w);
}
__device__ __forceinline__ void load8(const u16* p, u16* d) {
  union { uint4 q; u16 u[8]; } t;
  t.q = *reinterpret_cast<const uint4*>(p);
#pragma unroll
  for (int i = 0; i < 8; ++i) d[i] = t.u[i];
}

// ---------------------------------------------------------------------------
// 1x1-conv GEMM (R11-proven): Out[n,o,l] = sum_c W[o,c]*X[n,c,l] + bias[o]
// W fp32 (f2bf in staging regs). X bf16 or fp32 (TX).
// mode 0: OutBf (bf16)
// mode 1: Out32[idx] = v + Res[idx]  (fp32 residual/out; Res may alias Out32)
// Block tile 64(O) x LT(L), BK=32, 4 waves; each wave computes 16(O) x LT.
// T14 reg-prefetch: K-tile t+1's global loads issue during tile t's compute.
// L=1024 convs: grid 8x8x8 = 512 blocks = 2/CU (R17 lesson: 1/CU tiles lose).
// ---------------------------------------------------------------------------
template <typename TX, int LT>
__global__ __launch_bounds__(256) void gemm_conv(
    const TX* __restrict__ X, const float* __restrict__ W,
    const float* __restrict__ Bias,
    u16* __restrict__ OutBf, float* __restrict__ Out32,
    const float* __restrict__ Res,
    int Cin, int L, int O, int mode)
{
  constexpr int NL = LT / 16;                 // acc tiles; l per thread per ch
  __shared__ __align__(16) u16 As[64][40];    // [o][k]
  __shared__ __align__(16) u16 Bs[LT][40];    // transposed: [l][k]
  const int tid = threadIdx.x;
  const int wave = tid >> 6;
  const int lane = tid & 63;
  const int n = blockIdx.z;
  const int o0 = blockIdx.x * 64;
  const int l0 = blockIdx.y * LT;
  const TX* Xn = X + (size_t)n * Cin * L;

  // staging ownership
  const int ao = tid >> 2, akc = (tid & 3) * 8;        // A: row o, 8 k
  const int c2 = (tid & 15) * 2, lt0 = (tid >> 4) * NL; // B: 2 channels, NL l
  const float* wp = W + (size_t)(o0 + ao) * Cin + akc;
  const TX* xp0 = Xn + (size_t)c2 * L + l0 + lt0;
  const TX* xp1 = xp0 + L;

  f32x4 acc[NL];
#pragma unroll
  for (int i = 0; i < NL; ++i) acc[i] = (f32x4){0.f, 0.f, 0.f, 0.f};

  const int row = lane & 15;
  const int kh = (lane >> 4) * 8;

  // ---- prefetch K-tile 0 ----
  float4 wa = *reinterpret_cast<const float4*>(wp);
  float4 wb = *reinterpret_cast<const float4*>(wp + 4);
  u16 blo[NL], bhi[NL];
#pragma unroll
  for (int ch = 0; ch < NL; ch += 4) {
    load4(xp0 + ch, blo + ch);
    load4(xp1 + ch, bhi + ch);
  }

  const int nK = Cin >> 5;
  for (int kt = 0; kt < nK; ++kt) {
    // ---- ds_write prefetched A (b128) ----
    {
      union { uint4 q; u16 u[8]; } ap;
      ap.u[0] = f2bf(wa.x); ap.u[1] = f2bf(wa.y);
      ap.u[2] = f2bf(wa.z); ap.u[3] = f2bf(wa.w);
      ap.u[4] = f2bf(wb.x); ap.u[5] = f2bf(wb.y);
      ap.u[6] = f2bf(wb.z); ap.u[7] = f2bf(wb.w);
      *reinterpret_cast<uint4*>(&As[ao][akc]) = ap.q;
    }
    // ---- ds_write prefetched B (paired-channel u32) ----
#pragma unroll
    for (int j = 0; j < NL; ++j)
      *reinterpret_cast<unsigned int*>(&Bs[lt0 + j][c2]) =
          (unsigned int)blo[j] | ((unsigned int)bhi[j] << 16);
    __syncthreads();

    // ---- issue next K-tile's global loads (hide under compute) ----
    if (kt + 1 < nK) {
      const int k0 = (kt + 1) * 32;
      wa = *reinterpret_cast<const float4*>(wp + k0);
      wb = *reinterpret_cast<const float4*>(wp + k0 + 4);
#pragma unroll
      for (int ch = 0; ch < NL; ch += 4) {
        load4(xp0 + (size_t)k0 * L + ch, blo + ch);
        load4(xp1 + (size_t)k0 * L + ch, bhi + ch);
      }
    }

    // ---- compute ----
    bf16x8 a = *reinterpret_cast<const bf16x8*>(&As[wave * 16 + row][kh]);
#pragma unroll
    for (int lt = 0; lt < NL; ++lt) {
      bf16x8 b = *reinterpret_cast<const bf16x8*>(&Bs[lt * 16 + row][kh]);
      acc[lt] = __builtin_amdgcn_mfma_f32_16x16x32_bf16(a, b, acc[lt], 0, 0, 0);
    }
    __syncthreads();
  }

  const int col = lane & 15;
  const int r0 = (lane >> 4) * 4;
#pragma unroll
  for (int lt = 0; lt < NL; ++lt) {
    const int ll = l0 + lt * 16 + col;
#pragma unroll
    for (int j = 0; j < 4; ++j) {
      const int oo = o0 + wave * 16 + r0 + j;
      float v = acc[lt][j] + Bias[oo];
      const size_t idx = ((size_t)n * O + oo) * L + ll;
      if (mode == 1) {
        Out32[idx] = v + Res[idx];
      } else {
        OutBf[idx] = f2bf(v);
      }
    }
  }
}

// ---------------------------------------------------------------------------
// qkv GEMM: 128(O) x 128(L), BK=32, 4 waves; wave owns 32 O rows (2 groups
// of 16, flash-style) x 128 L -> 16 MFMA per wave per barrier pair (2x R11).
// Grid 12x8x8 = 768 blocks = 3/CU -- occupancy-safe for the bigger tile.
// bf16 X only, bf16 out, no residual. T14 reg-prefetch.
// ---------------------------------------------------------------------------
__global__ __launch_bounds__(256) void gemm_qkv(
    const u16* __restrict__ X, const float* __restrict__ W,
    const float* __restrict__ Bias, u16* __restrict__ OutBf,
    int Cin, int L, int O)
{
  __shared__ __align__(16) u16 As[128][40];   // [o][k]
  __shared__ __align__(16) u16 Bs[128][40];   // transposed: [l][k]
  const int tid = threadIdx.x;
  const int wave = tid >> 6;
  const int lane = tid & 63;
  const int n = blockIdx.z;
  const int o0 = blockIdx.x * 128;
  const int l0 = blockIdx.y * 128;
  const u16* Xn = X + (size_t)n * Cin * L;

  // staging ownership
  const int ao = tid >> 1, ak = (tid & 1) * 16;        // A: row o, 16 k
  const int c2 = (tid & 15) * 2, lt0 = (tid >> 4) * 8; // B: 2 ch, 8 l
  const float* wp = W + (size_t)(o0 + ao) * Cin + ak;
  const u16* xp0 = Xn + (size_t)c2 * L + l0 + lt0;
  const u16* xp1 = xp0 + L;

  f32x4 acc[2][8];
#pragma unroll
  for (int g = 0; g < 2; ++g)
#pragma unroll
    for (int i = 0; i < 8; ++i) acc[g][i] = (f32x4){0.f, 0.f, 0.f, 0.f};

  const int row = lane & 15;
  const int kh = (lane >> 4) * 8;

  // ---- prefetch K-tile 0 ----
  float4 w0 = *reinterpret_cast<const float4*>(wp);
  float4 w1 = *reinterpret_cast<const float4*>(wp + 4);
  float4 w2 = *reinterpret_cast<const float4*>(wp + 8);
  float4 w3 = *reinterpret_cast<const float4*>(wp + 12);
  u16 blo[8], bhi[8];
  load8(xp0, blo);
  load8(xp1, bhi);

  const int nK = Cin >> 5;
  for (int kt = 0; kt < nK; ++kt) {
    // ---- ds_write prefetched A (2 x b128) ----
    {
      union { uint4 q; u16 u[8]; } ap;
      ap.u[0] = f2bf(w0.x); ap.u[1] = f2bf(w0.y);
      ap.u[2] = f2bf(w0.z); ap.u[3] = f2bf(w0.w);
      ap.u[4] = f2bf(w1.x); ap.u[5] = f2bf(w1.y);
      ap.u[6] = f2bf(w1.z); ap.u[7] = f2bf(w1.w);
      *reinterpret_cast<uint4*>(&As[ao][ak]) = ap.q;
      ap.u[0] = f2bf(w2.x); ap.u[1] = f2bf(w2.y);
      ap.u[2] = f2bf(w2.z); ap.u[3] = f2bf(w2.w);
      ap.u[4] = f2bf(w3.x); ap.u[5] = f2bf(w3.y);
      ap.u[6] = f2bf(w3.z); ap.u[7] = f2bf(w3.w);
      *reinterpret_cast<uint4*>(&As[ao][ak + 8]) = ap.q;
    }
    // ---- ds_write prefetched B (8 paired-channel u32) ----
#pragma unroll
    for (int j = 0; j < 8; ++j)
      *reinterpret_cast<unsigned int*>(&Bs[lt0 + j][c2]) =
          (unsigned int)blo[j] | ((unsigned int)bhi[j] << 16);
    __syncthreads();

    // ---- issue next K-tile's global loads (hide under compute) ----
    if (kt + 1 < nK) {
      const int k0 = (kt + 1) * 32;
      w0 = *reinterpret_cast<const float4*>(wp + k0);
      w1 = *reinterpret_cast<const float4*>(wp + k0 + 4);
      w2 = *reinterpret_cast<const float4*>(wp + k0 + 8);
      w3 = *reinterpret_cast<const float4*>(wp + k0 + 12);
      load8(xp0 + (size_t)k0 * L, blo);
      load8(xp1 + (size_t)k0 * L, bhi);
    }

    // ---- compute: 2 A-groups x 8 B-tiles = 16 MFMA/wave ----
    bf16x8 a0 = *reinterpret_cast<const bf16x8*>(&As[wave * 32 + row][kh]);
    bf16x8 a1 = *reinterpret_cast<const bf16x8*>(&As[wave * 32 + 16 + row][kh]);
#pragma unroll
    for (int lt = 0; lt < 8; ++lt) {
      bf16x8 b = *reinterpret_cast<const bf16x8*>(&Bs[lt * 16 + row][kh]);
      acc[0][lt] = __builtin_amdgcn_mfma_f32_16x16x32_bf16(a0, b, acc[0][lt], 0, 0, 0);
      acc[1][lt] = __builtin_amdgcn_mfma_f32_16x16x32_bf16(a1, b, acc[1][lt], 0, 0, 0);
    }
    __syncthreads();
  }

  const int col = lane & 15;
  const int r0 = (lane >> 4) * 4;
#pragma unroll
  for (int g = 0; g < 2; ++g)
#pragma unroll
    for (int lt = 0; lt < 8; ++lt) {
      const int ll = l0 + lt * 16 + col;
#pragma unroll
      for (int j = 0; j < 4; ++j) {
        const int oo = o0 + wave * 32 + g * 16 + r0 + j;
        OutBf[((size_t)n * O + oo) * L + ll] = f2bf(acc[g][lt][j] + Bias[oo]);
      }
    }
}

// ---------------------------------------------------------------------------
// MFMA flash attention (R19-proven, 61.3 us): XOR-swizzled LDS (T2),
// reg-prefetch staging (T14), phase-aliased 40 KB LDS, setprio (T5),
// exp2-domain softmax, defer-max (T13) with DEFERRED max-reduction (16-lane
// shuffle reduce only inside the rare rescale branch), per-lane deferred
// l-reduction.  Block = (head bh, 128-q tile), 4 waves; wave owns 32 q-rows.
//   phase 0: Qs[128*128] (32 KB) - staged coalesced, hoisted to regs, dead
//   phase 1: Ks[64*128] | Ps[128*64] | Vt[64*64] alias over Qs
// launch_bounds(256,2): (256,4) squeezes to 64 VGPR -> 200MB spill (r9/r10);
// 8-wave variant (r20) doubles bank conflicts + drops VGPR to 72 -> +16 us.
// ---------------------------------------------------------------------------
__global__ __launch_bounds__(256, 2) void flash_attn(
    const u16* __restrict__ qA, int qA_C, int qA_off,
    const u16* __restrict__ qB,
    const u16* __restrict__ kA, int kA_C, int kA_off,
    const u16* __restrict__ kB,
    const u16* __restrict__ V, int v_C, int v_off,
    u16* __restrict__ Out, int S_len, float qscale)
{
  __shared__ __align__(16) u16 smem[20480];   // 40 KB
  u16* const Qs = smem;                        // [128*128] phase 0
  u16* const Ks = smem;                        // [64*128]  phase 1
  u16* const Ps = smem + 8192;                 // [128*64]  phase 1
  u16* const Vt = smem + 16384;                // [64*64]   phase 1

  const int tid = threadIdx.x;
  const int wave = tid >> 6, lane = tid & 63;
  const int b = blockIdx.y >> 3, h = blockIdx.y & 7;
  const int t0 = blockIdx.x * 128;
  const int l16 = lane & 15, q4 = lane >> 4;
  const int swz = (l16 & 7) << 3;

  // per-thread channel pair for Q/K staging (c2 even; c2,c2+1 same source)
  const int c2 = (tid & 63) * 2;
  const u16* q0 = (c2 < 64)
      ? qA + ((size_t)b * qA_C + qA_off + h * 64 + c2) * 1024 + t0
      : qB + ((size_t)b * 512 + h * 64 + (c2 - 64)) * 1024 + t0;
  const u16* q1 = q0 + 1024;
  const u16* k0 = (c2 < 64)
      ? kA + ((size_t)b * kA_C + kA_off + h * 64 + c2) * (size_t)S_len
      : kB + ((size_t)b * 512 + h * 64 + (c2 - 64)) * (size_t)S_len;
  const u16* k1 = k0 + S_len;
  const u16* vb = V + ((size_t)b * v_C + v_off + h * 64) * (size_t)S_len;

  const int s8 = (tid >> 6) * 8;            // K staging rows: s8..s8+7, +32
  const int cv0 = tid >> 3, sb0 = (tid & 7) * 8;          // V part 0
  const int cv1 = (tid + 256) >> 3, sb1 = sb0;            // V part 1

  // ---- prefetch K/V tile 0 into regs ----
  uint4 kr0a = *reinterpret_cast<const uint4*>(k0 + s8);
  uint4 kr0c = *reinterpret_cast<const uint4*>(k1 + s8);
  uint4 kr1a = *reinterpret_cast<const uint4*>(k0 + s8 + 32);
  uint4 kr1c = *reinterpret_cast<const uint4*>(k1 + s8 + 32);
  uint4 vr0 = *reinterpret_cast<const uint4*>(vb + (size_t)cv0 * S_len + sb0);
  uint4 vr1 = *reinterpret_cast<const uint4*>(vb + (size_t)cv1 * S_len + sb1);

  // ---- phase 0: stage Q (qscale folded), paired u32 swizzled writes ----
#pragma unroll
  for (int it = 0; it < 4; ++it) {
    const int t8 = (tid >> 6) * 8 + it * 32;
    union { uint4 q; u16 u[8]; } a, c;
    a.q = *reinterpret_cast<const uint4*>(q0 + t8);
    c.q = *reinterpret_cast<const uint4*>(q1 + t8);
#pragma unroll
    for (int j = 0; j < 8; ++j) {
      const unsigned int w =
          cvtpk(bf2f(a.u[j]) * qscale, bf2f(c.u[j]) * qscale);
      *reinterpret_cast<unsigned int*>(&Qs[(t8 + j) * 128 + (c2 ^ (j << 3))]) = w;
    }
  }
  __syncthreads();

  // hoist Q fragments (2 row-groups x 4 k-chunks), reused every tile
  bf16x8 qf[2][4];
#pragma unroll
  for (int g = 0; g < 2; ++g)
#pragma unroll
    for (int kk = 0; kk < 4; ++kk)
      qf[g][kk] = *reinterpret_cast<const bf16x8*>(
          &Qs[(wave * 32 + g * 16 + l16) * 128 + ((kk * 32 + q4 * 8) ^ swz)]);
  __syncthreads();   // Qs dead; Ks/Ps/Vt may now overwrite

  // l_run holds PER-LANE partial sums (corr is uniform within 16-lane group);
  // reduced across the group once in the epilogue.
  float m_run[2][4], l_run[2][4];
  f32x4 o_acc[2][4];
#pragma unroll
  for (int g = 0; g < 2; ++g)
#pragma unroll
    for (int j = 0; j < 4; ++j) {
      m_run[g][j] = -1e30f; l_run[g][j] = 0.f;
      o_acc[g][j] = (f32x4){0.f, 0.f, 0.f, 0.f};
    }

  const int NT = S_len >> 6;
  for (int t = 0; t < NT; ++t) {
    // ---- ds_write prefetched K (u32 pairs, swizzled) ----
    {
      union { uint4 q; u16 u[8]; } a, c;
      a.q = kr0a; c.q = kr0c;
#pragma unroll
      for (int j = 0; j < 8; ++j)
        *reinterpret_cast<unsigned int*>(&Ks[(s8 + j) * 128 + (c2 ^ (j << 3))]) =
            (unsigned int)a.u[j] | ((unsigned int)c.u[j] << 16);
      a.q = kr1a; c.q = kr1c;
#pragma unroll
      for (int j = 0; j < 8; ++j)
        *reinterpret_cast<unsigned int*>(&Ks[(s8 + 32 + j) * 128 + (c2 ^ (j << 3))]) =
            (unsigned int)a.u[j] | ((unsigned int)c.u[j] << 16);
    }
    // ---- ds_write prefetched V (b128, swizzled) ----
    *reinterpret_cast<uint4*>(&Vt[cv0 * 64 + (sb0 ^ ((cv0 & 7) << 3))]) = vr0;
    *reinterpret_cast<uint4*>(&Vt[cv1 * 64 + (sb1 ^ ((cv1 & 7) << 3))]) = vr1;
    __syncthreads();

    // ---- issue next tile's global loads (complete under this tile's compute) ----
    if (t + 1 < NT) {
      const int sc = (t + 1) * 64;
      kr0a = *reinterpret_cast<const uint4*>(k0 + sc + s8);
      kr0c = *reinterpret_cast<const uint4*>(k1 + sc + s8);
      kr1a = *reinterpret_cast<const uint4*>(k0 + sc + s8 + 32);
      kr1c = *reinterpret_cast<const uint4*>(k1 + sc + s8 + 32);
      vr0 = *reinterpret_cast<const uint4*>(vb + (size_t)cv0 * S_len + sc + sb0);
      vr1 = *reinterpret_cast<const uint4*>(vb + (size_t)cv1 * S_len + sc + sb1);
    }

    // ---- QK^T: S[q][s]; q-groups g=0,1 share each K fragment ----
    f32x4 sacc[2][4];
#pragma unroll
    for (int g = 0; g < 2; ++g)
#pragma unroll
      for (int st = 0; st < 4; ++st) sacc[g][st] = (f32x4){0.f, 0.f, 0.f, 0.f};
    __builtin_amdgcn_s_setprio(1);
#pragma unroll
    for (int st = 0; st < 4; ++st) {
#pragma unroll
      for (int kk = 0; kk < 4; ++kk) {
        bf16x8 kf = *reinterpret_cast<const bf16x8*>(
            &Ks[(st * 16 + l16) * 128 + ((kk * 32 + q4 * 8) ^ swz)]);
        sacc[0][st] = __builtin_amdgcn_mfma_f32_16x16x32_bf16(qf[0][kk], kf, sacc[0][st], 0, 0, 0);
        sacc[1][st] = __builtin_amdgcn_mfma_f32_16x16x32_bf16(qf[1][kk], kf, sacc[1][st], 0, 0, 0);
      }
    }
    __builtin_amdgcn_s_setprio(0);

    // ---- per-lane partial max (NO cross-lane reduce on the common path) ----
    float mt[2][4];
#pragma unroll
    for (int g = 0; g < 2; ++g)
#pragma unroll
      for (int j = 0; j < 4; ++j)
        mt[g][j] = fmaxf(fmaxf(sacc[g][0][j], sacc[g][1][j]),
                         fmaxf(sacc[g][2][j], sacc[g][3][j]));

    // ---- defer-max (T13): row-max > m+THR iff some lane's partial > m+THR ----
    bool grow = false;
#pragma unroll
    for (int g = 0; g < 2; ++g)
#pragma unroll
      for (int j = 0; j < 4; ++j)
        grow = grow || (mt[g][j] > m_run[g][j] + 8.f);
    if (__any(grow)) {
      // full 16-lane reduce + rescale (rare; first tile always enters,
      // so m_run is properly row-uniform thereafter)
#pragma unroll
      for (int g = 0; g < 2; ++g) {
#pragma unroll
        for (int d = 1; d < 16; d <<= 1)
#pragma unroll
          for (int j = 0; j < 4; ++j)
            mt[g][j] = fmaxf(mt[g][j], __shfl_xor(mt[g][j], d));
#pragma unroll
        for (int j = 0; j < 4; ++j) {
          const float mn = fmaxf(m_run[g][j], mt[g][j]);
          const float corr = exp2f(m_run[g][j] - mn);
          m_run[g][j] = mn;
          l_run[g][j] *= corr;
#pragma unroll
          for (int ct = 0; ct < 4; ++ct) o_acc[g][ct][j] *= corr;
        }
      }
    }

    // ---- P = exp2(s - m), per-lane l partials, write P (wave-private) ----
#pragma unroll
    for (int g = 0; g < 2; ++g)
#pragma unroll
      for (int st = 0; st < 4; ++st)
#pragma unroll
        for (int j = 0; j < 4; ++j) {
          const float p = exp2f(sacc[g][st][j] - m_run[g][j]);
          l_run[g][j] += p;
          Ps[(wave * 32 + g * 16 + q4 * 4 + j) * 64 +
             ((st * 16 + l16) ^ (((q4 * 4 + j) & 7) << 3))] = f2bf(p);
        }

    // ---- PV: O[q][cv] += P[q][s] * V[s][cv]; V fragments shared by g ----
    bf16x8 pa[2][2];
#pragma unroll
    for (int g = 0; g < 2; ++g)
#pragma unroll
      for (int ks = 0; ks < 2; ++ks)
        pa[g][ks] = *reinterpret_cast<const bf16x8*>(
            &Ps[(wave * 32 + g * 16 + l16) * 64 + ((ks * 32 + q4 * 8) ^ swz)]);
    __builtin_amdgcn_s_setprio(1);
#pragma unroll
    for (int ct = 0; ct < 4; ++ct) {
#pragma unroll
      for (int ks = 0; ks < 2; ++ks) {
        bf16x8 vf = *reinterpret_cast<const bf16x8*>(
            &Vt[(ct * 16 + l16) * 64 + ((ks * 32 + q4 * 8) ^ swz)]);
        o_acc[0][ct] = __builtin_amdgcn_mfma_f32_16x16x32_bf16(pa[0][ks], vf, o_acc[0][ct], 0, 0, 0);
        o_acc[1][ct] = __builtin_amdgcn_mfma_f32_16x16x32_bf16(pa[1][ks], vf, o_acc[1][ct], 0, 0, 0);
      }
    }
    __builtin_amdgcn_s_setprio(0);
    __syncthreads();  // all LDS reads done before next tile's ds_writes
  }

  // ---- epilogue: reduce l partials across 16-lane groups, O /= l, store ----
#pragma unroll
  for (int g = 0; g < 2; ++g) {
#pragma unroll
    for (int d = 1; d < 16; d <<= 1)
#pragma unroll
      for (int j = 0; j < 4; ++j) l_run[g][j] += __shfl_xor(l_run[g][j], d);
    float inv[4];
#pragma unroll
    for (int j = 0; j < 4; ++j) inv[j] = 1.f / l_run[g][j];
    const size_t obase =
        ((size_t)b * 512 + h * 64) * 1024 + t0 + wave * 32 + g * 16 + q4 * 4;
#pragma unroll
    for (int ct = 0; ct < 4; ++ct) {
      union { unsigned long long d; u16 u[4]; } pk;
#pragma unroll
      for (int j = 0; j < 4; ++j) pk.u[j] = f2bf(o_acc[g][ct][j] * inv[j]);
      *reinterpret_cast<unsigned long long*>(
          Out + obase + (size_t)(ct * 16 + l16) * 1024) = pk.d;
    }
  }
}

// ---------------------------------------------------------------------------
// Workspace plan (48 MB total; all lifetimes provably disjoint, stream-ordered)
//   A [ 0, 8M): norm1(w1,r2) -> norm2(w7,r8) -> smalls(w9..12, r13)
//   B [ 8,32M): qkv(w2,r5) -> cq = B head (w8,r13)
//   C [32,40M): ipos(w4; r5,r13)
//   D [40,48M): iposr(w3,r4) -> attn1(w5,r6) -> cattn(w13,r14)
//   xf32 lives in d_out (w6; r7; r14 as Res; w14 final) — element-wise self-alias ok
// ---------------------------------------------------------------------------
extern "C" void kernel_launch(void* const* d_in, const int* in_sizes, int n_in,
                              void* d_out, int out_size, void* d_ws, size_t ws_size,
                              hipStream_t stream) {
  const float* X_in        = (const float*)d_in[0];
  const float* xf_out      = (const float*)d_in[1];
  const float* obj_cont    = (const float*)d_in[2];
  const float* obj_desc    = (const float*)d_in[3];
  const float* ipce        = (const float*)d_in[4];
  const float* gn_qkv_g    = (const float*)d_in[5];
  const float* gn_qkv_b    = (const float*)d_in[6];
  const float* W_self_qkv  = (const float*)d_in[7];
  const float* b_self_qkv  = (const float*)d_in[8];
  const float* W_cross_q   = (const float*)d_in[9];
  const float* b_cross_q   = (const float*)d_in[10];
  const float* W_content   = (const float*)d_in[11];
  const float* b_content   = (const float*)d_in[12];
  const float* W_pos       = (const float*)d_in[13];
  const float* b_pos       = (const float*)d_in[14];
  const float* gn_desc_g   = (const float*)d_in[15];
  const float* gn_desc_b   = (const float*)d_in[16];
  const float* gn_cpos_g   = (const float*)d_in[17];
  const float* gn_cpos_b   = (const float*)d_in[18];
  const float* gn_ipos_g   = (const float*)d_in[19];
  const float* gn_ipos_b   = (const float*)d_in[20];
  const float* W_self_out  = (const float*)d_in[21];
  const float* b_self_out  = (const float*)d_in[22];
  const float* W_cross_out = (const float*)d_in[23];
  const float* b_cross_out = (const float*)d_in[24];

  char* base = (char*)d_ws;
  u16* A = (u16*)base;                       // 8 MB region
  u16* B = (u16*)(base + 8 * 1024 * 1024);   // 24 MB region
  u16* C = (u16*)(base + 32 * 1024 * 1024);  // 8 MB region
  u16* D = (u16*)(base + 40 * 1024 * 1024);  // 8 MB region

  u16* norm1 = A;
  u16* norm2 = A;
  u16* cposr   = A;
  u16* cpos    = A + 262144;
  u16* content = A + 2 * 262144;
  u16* kvbuf   = A + 3 * 262144;   // 524288 elems
  u16* qkv  = B;
  u16* cq   = B;
  u16* ipos = C;
  u16* iposr = D;
  u16* attn1 = D;
  u16* cattn = D;
  float* xf32 = (float*)d_out;
  float* outp = (float*)d_out;

  // scale^2 = 128^-0.5; fold log2(e) for exp2-domain softmax
  const float qscale = 0.08838834764831845f * 1.4426950408889634f;
  dim3 blk(256);
  dim3 blkgn(1024);

  // 1. norm1 = GN(x)
  gn_kernel<float><<<dim3(256), blkgn, 0, stream>>>(X_in, norm1, gn_qkv_g, gn_qkv_b,
                                                    nullptr, 1.f, 512, 1024, 16);
  // 2. qkv = conv(norm1, W_self_qkv)  [128x128 tile, 16 MFMA/wave/iter, 3/CU]
  gemm_qkv<<<dim3(12, 8, 8), blk, 0, stream>>>(norm1, W_self_qkv, b_self_qkv,
                                               qkv, 512, 1024, 1536);
  // 3. iposr = conv(ipce, W_pos)   [64x128 tile, 2/CU]
  gemm_conv<float, 128><<<dim3(8, 8, 8), blk, 0, stream>>>(ipce, W_pos, b_pos, iposr,
                                                           nullptr, nullptr,
                                                           512, 1024, 512, 0);
  // 4. ipos = GN(iposr)
  gn_kernel<u16><<<dim3(256), blkgn, 0, stream>>>(iposr, ipos, gn_ipos_g, gn_ipos_b,
                                                  nullptr, 1.f, 512, 1024, 16);
  // 5. self-attention -> attn1 (flash MFMA, 128-q tiles)
  flash_attn<<<dim3(8, 64), blk, 0, stream>>>(qkv, 1536, 0, ipos,
                                              qkv, 1536, 512, ipos,
                                              qkv, 1536, 1024,
                                              attn1, 1024, qscale);
  // 6. xf32 = x + conv(attn1, W_self_out)   [xf32 = d_out]
  gemm_conv<u16, 128><<<dim3(8, 8, 8), blk, 0, stream>>>(attn1, W_self_out, b_self_out,
                                                         nullptr, xf32, X_in,
                                                         512, 1024, 512, 1);
  // 7. norm2 = GN(xf32)
  gn_kernel<float><<<dim3(256), blkgn, 0, stream>>>(xf32, norm2, gn_qkv_g, gn_qkv_b,
                                                    nullptr, 1.f, 512, 1024, 16);
  // 8. cq = conv(norm2, W_cross_q)
  gemm_conv<u16, 128><<<dim3(8, 8, 8), blk, 0, stream>>>(norm2, W_cross_q, b_cross_q, cq,
                                                         nullptr, nullptr,
                                                         512, 1024, 512, 0);
  // 9. cposr = conv(obj_contour, W_pos)
  gemm_conv<float, 64><<<dim3(8, 1, 8), blk, 0, stream>>>(obj_cont, W_pos, b_pos, cposr,
                                                          nullptr, nullptr,
                                                          512, 64, 512, 0);
  // 10. cpos = GN(cposr)
  gn_kernel<u16><<<dim3(256), blkgn, 0, stream>>>(cposr, cpos, gn_cpos_g, gn_cpos_b,
                                                  nullptr, 1.f, 512, 64, 16);
  // 11. content = (xf_out + GN(obj_desc)) / 2
  gn_kernel<float><<<dim3(256), blkgn, 0, stream>>>(obj_desc, content, gn_desc_g,
                                                    gn_desc_b, xf_out, 0.5f, 512, 64, 16);
  // 12. kv = conv(content, W_content)
  gemm_conv<u16, 64><<<dim3(16, 1, 8), blk, 0, stream>>>(content, W_content, b_content,
                                                         kvbuf, nullptr, nullptr,
                                                         512, 64, 1024, 0);
  // 13. cross-attention -> cattn (flash MFMA, single K-tile)
  flash_attn<<<dim3(8, 64), blk, 0, stream>>>(cq, 512, 0, ipos,
                                              kvbuf, 1024, 0, cpos,
                                              kvbuf, 1024, 512,
                                              cattn, 64, qscale);
  // 14. out = xf32 + conv(cattn, W_cross_out)   [in-place on d_out]
  gemm_conv<u16, 128><<<dim3(8, 8, 8), blk, 0, stream>>>(cattn, W_cross_out, b_cross_out,
                                                         nullptr, outp, xf32,
                                                         512, 1024, 512, 1);
}